// Round 5
// baseline (137.015 us; speedup 1.0000x reference)
//
#include <hip/hip_runtime.h>

// CALIBRATION ROUND: launch the R3 fused kernel 3x back-to-back to separate
// fixed harness/graph overhead (OH) from true kernel time (T):
//   dur3 = OH + 3T,  dur1(R3) = OH + T = 49.0 us
// Each launch writes the identical full output -> deterministic and correct.

#define N1 8192
#define N2 8192
#define D  8
#define ROWS 32

typedef float f32x4 __attribute__((ext_vector_type(4)));

__device__ __forceinline__ float rowsum8(const float* __restrict__ p) {
    const f32x4* q = reinterpret_cast<const f32x4*>(p);
    f32x4 a = q[0];
    f32x4 b = q[1];
    return ((a.x + a.y) + (a.z + a.w)) + ((b.x + b.y) + (b.z + b.w));
}

__global__ void __launch_bounds__(256)
rbf_fused_kernel(const float* __restrict__ in1,
                 const float* __restrict__ in2,
                 const float* __restrict__ gamma_p,
                 f32x4* __restrict__ out) {
    const int cb = blockIdx.x;   // column chunk (1024 cols)
    const int rb = blockIdx.y;   // row group (ROWS rows)
    const int t  = threadIdx.x;

    __shared__ float s1s[ROWS];

    const int col0 = cb * 1024 + t * 4;
    float s20 = rowsum8(in2 + (size_t)(col0 + 0) * D);
    float s21 = rowsum8(in2 + (size_t)(col0 + 1) * D);
    float s22 = rowsum8(in2 + (size_t)(col0 + 2) * D);
    float s23 = rowsum8(in2 + (size_t)(col0 + 3) * D);

    if (t < ROWS) {
        s1s[t] = rowsum8(in1 + (size_t)(rb * ROWS + t) * D);
    }
    const float g = gamma_p[0];
    __syncthreads();

    f32x4* __restrict__ orow = out + (size_t)(rb * ROWS) * (N2 / 4) + cb * 256 + t;

    #pragma unroll 4
    for (int r = 0; r < ROWS; ++r) {
        const float s1 = s1s[r];
        float d0 = s1 - s20;
        float d1 = s1 - s21;
        float d2 = s1 - s22;
        float d3 = s1 - s23;
        f32x4 v;
        v.x = __expf(d0 * d0) * g;
        v.y = __expf(d1 * d1) * g;
        v.z = __expf(d2 * d2) * g;
        v.w = __expf(d3 * d3) * g;
        __builtin_nontemporal_store(v, orow);
        orow += N2 / 4;
    }
}

extern "C" void kernel_launch(void* const* d_in, const int* in_sizes, int n_in,
                              void* d_out, int out_size, void* d_ws, size_t ws_size,
                              hipStream_t stream) {
    const float* in1     = (const float*)d_in[0];
    const float* in2     = (const float*)d_in[1];
    const float* gamma_p = (const float*)d_in[2];
    f32x4* out = (f32x4*)d_out;

    dim3 block(256);
    dim3 grid(N2 / 1024, N1 / ROWS);   // (8, 256)

    // 3 identical launches, stream-serialized.
    rbf_fused_kernel<<<grid, block, 0, stream>>>(in1, in2, gamma_p, out);
    rbf_fused_kernel<<<grid, block, 0, stream>>>(in1, in2, gamma_p, out);
    rbf_fused_kernel<<<grid, block, 0, stream>>>(in1, in2, gamma_p, out);
}

// Round 6
// 49.082 us; speedup vs baseline: 2.7915x; 2.7915x over previous
//
#include <hip/hip_runtime.h>

// FINAL: out[i,j] = exp((s1[i]-s2[j])^2) * gamma, fused single-sweep kernel.
// Each block: 32 x 1024 output tile; s2 (4 cols/thread) in registers, s1 via
// LDS broadcast; steady-state loop is pure compute + NT store (no global loads).
// Measured (R5 calibration): 44 us true kernel time = 6.1 TB/s sustained write
// BW = 97% of the achievable streaming ceiling; +5 us fixed harness overhead.

#define N1 8192
#define N2 8192
#define D  8
#define ROWS 32

typedef float f32x4 __attribute__((ext_vector_type(4)));

__device__ __forceinline__ float rowsum8(const float* __restrict__ p) {
    const f32x4* q = reinterpret_cast<const f32x4*>(p);
    f32x4 a = q[0];
    f32x4 b = q[1];
    return ((a.x + a.y) + (a.z + a.w)) + ((b.x + b.y) + (b.z + b.w));
}

__global__ void __launch_bounds__(256)
rbf_fused_kernel(const float* __restrict__ in1,
                 const float* __restrict__ in2,
                 const float* __restrict__ gamma_p,
                 f32x4* __restrict__ out) {
    const int cb = blockIdx.x;   // column chunk (1024 cols)
    const int rb = blockIdx.y;   // row group (ROWS rows)
    const int t  = threadIdx.x;

    __shared__ float s1s[ROWS];

    const int col0 = cb * 1024 + t * 4;
    float s20 = rowsum8(in2 + (size_t)(col0 + 0) * D);
    float s21 = rowsum8(in2 + (size_t)(col0 + 1) * D);
    float s22 = rowsum8(in2 + (size_t)(col0 + 2) * D);
    float s23 = rowsum8(in2 + (size_t)(col0 + 3) * D);

    if (t < ROWS) {
        s1s[t] = rowsum8(in1 + (size_t)(rb * ROWS + t) * D);
    }
    const float g = gamma_p[0];
    __syncthreads();

    f32x4* __restrict__ orow = out + (size_t)(rb * ROWS) * (N2 / 4) + cb * 256 + t;

    #pragma unroll 4
    for (int r = 0; r < ROWS; ++r) {
        const float s1 = s1s[r];           // wave-uniform LDS broadcast
        float d0 = s1 - s20;
        float d1 = s1 - s21;
        float d2 = s1 - s22;
        float d3 = s1 - s23;
        f32x4 v;
        v.x = __expf(d0 * d0) * g;
        v.y = __expf(d1 * d1) * g;
        v.z = __expf(d2 * d2) * g;
        v.w = __expf(d3 * d3) * g;
        __builtin_nontemporal_store(v, orow);
        orow += N2 / 4;
    }
}

extern "C" void kernel_launch(void* const* d_in, const int* in_sizes, int n_in,
                              void* d_out, int out_size, void* d_ws, size_t ws_size,
                              hipStream_t stream) {
    const float* in1     = (const float*)d_in[0];
    const float* in2     = (const float*)d_in[1];
    const float* gamma_p = (const float*)d_in[2];
    f32x4* out = (f32x4*)d_out;

    dim3 block(256);
    dim3 grid(N2 / 1024, N1 / ROWS);   // (8, 256) = 2048 blocks
    rbf_fused_kernel<<<grid, block, 0, stream>>>(in1, in2, gamma_p, out);
}